// Round 1
// 835.276 us; speedup vs baseline: 1.1401x; 1.1401x over previous
//
#include <hip/hip_runtime.h>
#include <stdint.h>

#define D_MODEL 512
#define NHEADS 8
#define DK 64
#define NB 8192
#define NTOK 14
#define ROWS (NB*NTOK)   // 114688

typedef unsigned short ushort_t;
typedef __attribute__((ext_vector_type(8))) short short8;
typedef __attribute__((ext_vector_type(4))) short short4v;
typedef __attribute__((ext_vector_type(4))) float f32x4;

__device__ __forceinline__ float bf2f(ushort_t u) {
    return __uint_as_float(((unsigned int)u) << 16);
}
__device__ __forceinline__ ushort_t f2bf(float f) {
    unsigned int u = __float_as_uint(f);
    unsigned int r = (u + 0x7FFFu + ((u >> 16) & 1u)) >> 16;
    return (ushort_t)r;
}

// async 16B global->LDS: lds dest must be wave-uniform base; HW deposits lane i at base + i*16B
__device__ __forceinline__ void async_copy16(const ushort_t* g, ushort_t* l) {
    __builtin_amdgcn_global_load_lds(
        (const __attribute__((address_space(1))) void*)g,
        (__attribute__((address_space(3))) void*)l,
        16, 0, 0);
}

// fp32 -> bf16 conversion (rne), 4 elems/thread
__global__ void cvt_kernel(const float* __restrict__ src, ushort_t* __restrict__ dst, int n)
{
    int i = (blockIdx.x * blockDim.x + threadIdx.x) * 4;
    if (i + 3 < n) {
        float4 v = *(const float4*)(src + i);
        short4v o;
        o[0] = (short)f2bf(v.x);
        o[1] = (short)f2bf(v.y);
        o[2] = (short)f2bf(v.z);
        o[3] = (short)f2bf(v.w);
        *(short4v*)(dst + i) = o;
    }
}

// C[M x *] = A[M x 512] @ W^T + bias. A/W bf16, bias fp32, acc fp32.
// Output: bf16 to Cb if Cf==null, else fp32 to Cf.
// LDS: As/Bs (16KB) unioned with the 36KB epilogue staging buffer (never live
// simultaneously: last K-loop __syncthreads retires As/Bs before epilogue writes).
// 36864 B/block -> 4 blocks/CU (vs 53248 -> 3).
// XCD-aware bijective chunk swizzle: all col-tiles of a row-tile + consecutive
// row-tiles land on one XCD -> A-tile fetched from HBM ~once (was ~4x).
__global__ __launch_bounds__(256, 4) void gemm_bt(
    const ushort_t* __restrict__ A, int lda,
    const ushort_t* __restrict__ W0, const ushort_t* __restrict__ W1, const ushort_t* __restrict__ W2,
    const float* __restrict__ b0, const float* __restrict__ b1, const float* __restrict__ b2,
    ushort_t* __restrict__ Cb, float* __restrict__ Cf, int ldc)
{
    __shared__ __align__(16) char Shm[36864];
    ushort_t* As = (ushort_t*)Shm;            // 128*32 ushorts = 8192 B
    ushort_t* Bs = (ushort_t*)(Shm + 8192);   // 8192 B

    // bijective XCD chunk remap (m204): nwg need not be %8 here, formula handles it
    const int nwg = gridDim.x * gridDim.y;
    const int wg  = blockIdx.y * gridDim.x + blockIdx.x;   // hw linear id (x fastest)
    const int q8  = nwg >> 3, r8 = nwg & 7;
    const int xcd = wg & 7, idx = wg >> 3;
    const int cbase = (xcd < r8) ? xcd * (q8 + 1) : r8 * (q8 + 1) + (xcd - r8) * q8;
    const int newid = cbase + idx;
    const int ctile = newid % gridDim.x;      // col tile fast-varying within an XCD chunk
    const int rtile = newid / gridDim.x;

    const int m0 = rtile * 128;
    const int n0 = ctile * 128;
    const int wsel = n0 >> 9;
    const ushort_t* W    = (wsel == 0) ? W0 : ((wsel == 1) ? W1 : W2);
    const float*    bias = (wsel == 0) ? b0 : ((wsel == 1) ? b1 : b2);
    const int nw = n0 & 511;

    const int tid  = threadIdx.x;
    const int lane = tid & 63;
    const int wave = tid >> 6;
    const int quad = lane >> 4;
    const int c    = lane & 15;
    const int wm   = (wave & 1) * 64;
    const int wn   = (wave >> 1) * 64;

    f32x4 acc[4][4];
    #pragma unroll
    for (int i = 0; i < 4; ++i)
        #pragma unroll
        for (int j = 0; j < 4; ++j)
            acc[i][j] = (f32x4){0.f, 0.f, 0.f, 0.f};

    // chunk geometry: tile = 128 rows x 32 ushort = 512 chunks of 16B; chunk c
    // covers row c>>2, ushorts (c&3)*8.. and lands at LDS offset c*16B.
    for (int k0 = 0; k0 < 512; k0 += 32) {
        #pragma unroll
        for (int rnd = 0; rnd < 2; ++rnd) {
            int chunk = rnd * 256 + wave * 64 + lane;
            int row   = chunk >> 2;
            int kq    = (chunk & 3) * 8;
            int lbase = (rnd * 256 + wave * 64) * 8;   // wave-uniform ushort offset
            async_copy16(A + (size_t)(m0 + row) * lda + k0 + kq, &As[lbase]);
            async_copy16(W + (size_t)(nw + row) * 512 + k0 + kq, &Bs[lbase]);
        }
        __syncthreads();

        short8 af[4], bfr[4];
        #pragma unroll
        for (int i = 0; i < 4; ++i) {
            af[i]  = *(const short8*)&As[(wm + i * 16 + c) * 32 + quad * 8];
            bfr[i] = *(const short8*)&Bs[(wn + i * 16 + c) * 32 + quad * 8];
        }
        #pragma unroll
        for (int i = 0; i < 4; ++i)
            #pragma unroll
            for (int j = 0; j < 4; ++j)
                acc[i][j] = __builtin_amdgcn_mfma_f32_16x16x32_bf16(af[i], bfr[j], acc[i][j], 0, 0, 0);
        __syncthreads();
    }

    // Epilogue: per-wave LDS staging -> coalesced 16B stores.
    // acc C layout: col = wn + j*16 + c, row = wm + i*16 + quad*4 + r.
    if (Cf == nullptr) {
        // bf16 out: whole 64x64 wave tile, row stride 72 (pad kills bank conflicts)
        ushort_t* sl = (ushort_t*)Shm + wave * 64 * 72;
        #pragma unroll
        for (int i = 0; i < 4; ++i)
            #pragma unroll
            for (int j = 0; j < 4; ++j)
                #pragma unroll
                for (int r = 0; r < 4; ++r) {
                    int rl = i * 16 + quad * 4 + r;
                    int cl = j * 16 + c;
                    sl[rl * 72 + cl] = f2bf(acc[i][j][r] + bias[nw + wn + cl]);
                }
        #pragma unroll
        for (int t = 0; t < 8; ++t) {
            int rl = t * 8 + (lane >> 3);
            int cl = (lane & 7) * 8;
            short8 v = *(const short8*)&sl[rl * 72 + cl];
            *(short8*)&Cb[(size_t)(m0 + wm + rl) * ldc + n0 + wn + cl] = v;
        }
    } else {
        // fp32 out: two 32x64 half-tiles
        float* slf = (float*)Shm + wave * 32 * 72;
        #pragma unroll
        for (int half = 0; half < 2; ++half) {
            #pragma unroll
            for (int i2 = 0; i2 < 2; ++i2)
                #pragma unroll
                for (int j = 0; j < 4; ++j)
                    #pragma unroll
                    for (int r = 0; r < 4; ++r) {
                        int i  = half * 2 + i2;
                        int rl = i2 * 16 + quad * 4 + r;
                        int cl = j * 16 + c;
                        slf[rl * 72 + cl] = acc[i][j][r] + bias[nw + wn + cl];
                    }
            #pragma unroll
            for (int t = 0; t < 8; ++t) {
                int rl = t * 4 + (lane >> 4);
                int cl = (lane & 15) * 4;
                f32x4 v = *(const f32x4*)&slf[rl * 72 + cl];
                *(f32x4*)&Cf[(size_t)(m0 + wm + half * 32 + rl) * ldc + n0 + wn + cl] = v;
            }
            if (half == 0) __syncthreads();   // keep waves' slf reuse ordered (same wave only; cheap)
        }
    }
}

// One wave per (b, h). QKV: [ROWS][1536] bf16 (Q|K|V). O: [ROWS][512] bf16.
// Waves are fully independent: no block barrier. V staged per-wave into LDS
// TRANSPOSED (Vt[d][m]) with vectorized loads, so each PV B-fragment is one
// 16B-aligned ds_read_b128 (was 32 scalar 2B global loads per lane).
__global__ __launch_bounds__(256, 4) void attn_kernel(
    const ushort_t* __restrict__ QKV,
    const float* __restrict__ dist,
    const float* __restrict__ scale_p,
    const float* __restrict__ power_p,
    ushort_t* __restrict__ O)
{
    __shared__ __align__(16) ushort_t Pl[4][16 * 32];
    __shared__ __align__(16) ushort_t Vt[4][64 * 16];   // per-wave V^T: [dk][key]

    const int tid  = threadIdx.x;
    const int lane = tid & 63;
    const int wave = tid >> 6;
    const int id   = blockIdx.x * 4 + wave;   // b*8 + h
    const int b    = id >> 3;
    const int h    = id & 7;
    const int quad = lane >> 4;
    const int c    = lane & 15;

    const float scale = scale_p[0];
    const float power = power_p[0];

    const size_t rowbase = (size_t)b * NTOK;
    const int mrow = (c < NTOK) ? c : (NTOK - 1);

    // ---- stage V^T into LDS: lane covers row m = lane>>2, 16 dk at (lane&3)*16
    {
        int m  = lane >> 2;           // 0..15 (rows 14,15 zero-padded)
        int d0 = (lane & 3) * 16;
        short8 v0 = 0, v1 = 0;
        if (m < NTOK) {
            const ushort_t* vp = QKV + (rowbase + m) * 1536 + 1024 + h * 64 + d0;
            v0 = *(const short8*)vp;
            v1 = *(const short8*)(vp + 8);
        }
        #pragma unroll
        for (int j = 0; j < 8; ++j) {
            Vt[wave][(d0 + j) * 16 + m]     = (ushort_t)v0[j];
            Vt[wave][(d0 + 8 + j) * 16 + m] = (ushort_t)v1[j];
        }
    }

    // Q as A-operand (m = query = c, k = dk), K as B-operand (n = key = c, k = dk)
    const ushort_t* qp = QKV + (rowbase + mrow) * 1536 + h * 64 + quad * 8;
    short8 aq0 = *(const short8*)qp;
    short8 aq1 = *(const short8*)(qp + 32);
    const ushort_t* kp = QKV + (rowbase + mrow) * 1536 + 512 + h * 64 + quad * 8;
    short8 bk0 = *(const short8*)kp;
    short8 bk1 = *(const short8*)(kp + 32);

    f32x4 S = (f32x4){0.f, 0.f, 0.f, 0.f};
    S = __builtin_amdgcn_mfma_f32_16x16x32_bf16(aq0, bk0, S, 0, 0, 0);
    S = __builtin_amdgcn_mfma_f32_16x16x32_bf16(aq1, bk1, S, 0, 0, 0);

    // softmax over cols (key index) per row; C layout: col=c, row=quad*4+r
    float p4[4];
    #pragma unroll
    for (int r = 0; r < 4; ++r) {
        int row = quad * 4 + r;
        float s;
        if (c < NTOK && row < NTOK) {
            float d  = dist[row * NTOK + c];
            float dp = (d > 0.f) ? __expf(power * __logf(d)) : 0.f;
            float pri = scale / (1.f + dp);
            s = S[r] * 0.125f * pri;      // 1/sqrt(64)
        } else if (row >= NTOK) {
            s = 0.f;                       // garbage row, keep finite
        } else {
            s = -INFINITY;                 // col >= NTOK: excluded
        }
        float smax = s;
        #pragma unroll
        for (int off = 1; off < 16; off <<= 1)
            smax = fmaxf(smax, __shfl_xor(smax, off));
        float e = (c < NTOK) ? __expf(s - smax) : 0.f;
        float l = e;
        #pragma unroll
        for (int off = 1; off < 16; off <<= 1)
            l += __shfl_xor(l, off);
        p4[r] = e / l;
    }

    // P (C layout) -> LDS -> A-operand layout. Zero k=16..31 pad region.
    // Per-wave private region: no block barrier needed (compiler orders LDS ops).
    #pragma unroll
    for (int z = 0; z < 4; ++z) {
        int idx = lane * 4 + z;           // 0..255 over 16x16 pad region
        int zr = idx >> 4, zc = idx & 15;
        Pl[wave][zr * 32 + 16 + zc] = 0;
    }
    #pragma unroll
    for (int r = 0; r < 4; ++r)
        Pl[wave][(quad * 4 + r) * 32 + c] = f2bf(p4[r]);

    short8 pf = *(const short8*)&Pl[wave][c * 32 + quad * 8];

    // V as B-operand per 16-col dk tile: n = dk = t*16+c, k = key = quad*8+j
    // Vt[d][m] -> one ds_read_b128 per tile: elems j=0..7 = V[quad*8+j][t*16+c]
    f32x4 o[4];
    #pragma unroll
    for (int t = 0; t < 4; ++t) {
        short8 vf = *(const short8*)&Vt[wave][(t * 16 + c) * 16 + quad * 8];
        f32x4 z = (f32x4){0.f, 0.f, 0.f, 0.f};
        o[t] = __builtin_amdgcn_mfma_f32_16x16x32_bf16(pf, vf, z, 0, 0, 0);
    }

    #pragma unroll
    for (int r = 0; r < 4; ++r) {
        int row = quad * 4 + r;
        if (row < NTOK) {
            #pragma unroll
            for (int t = 0; t < 4; ++t)
                O[(rowbase + row) * 512 + h * 64 + t * 16 + c] = f2bf(o[t][r]);
        }
    }
}

extern "C" void kernel_launch(void* const* d_in, const int* in_sizes, int n_in,
                              void* d_out, int out_size, void* d_ws, size_t ws_size,
                              hipStream_t stream)
{
    const float* x     = (const float*)d_in[0];
    const float* Wq    = (const float*)d_in[1];
    const float* bq    = (const float*)d_in[2];
    const float* Wk    = (const float*)d_in[3];
    const float* bk    = (const float*)d_in[4];
    const float* Wv    = (const float*)d_in[5];
    const float* bv    = (const float*)d_in[6];
    const float* Wo    = (const float*)d_in[7];
    const float* bo    = (const float*)d_in[8];
    const float* scale = (const float*)d_in[9];
    const float* power = (const float*)d_in[10];
    const float* dist  = (const float*)d_in[11];

    float* out = (float*)d_out;

    // ws layout (bf16): [xb / att : ROWS*512][wb : 4*512*512][qkv : ROWS*1536]
    ushort_t* xb  = (ushort_t*)d_ws;                  // x bf16; reused as att
    ushort_t* wb  = xb + (size_t)ROWS * 512;
    ushort_t* qkv = wb + (size_t)4 * 512 * 512;

    dim3 blk(256);

    // fp32 -> bf16 converts
    const int NX = ROWS * 512;
    const int NW = 512 * 512;
    cvt_kernel<<<NX / 1024, blk, 0, stream>>>(x,  xb, NX);
    cvt_kernel<<<NW / 1024, blk, 0, stream>>>(Wq, wb + 0 * (size_t)NW, NW);
    cvt_kernel<<<NW / 1024, blk, 0, stream>>>(Wk, wb + 1 * (size_t)NW, NW);
    cvt_kernel<<<NW / 1024, blk, 0, stream>>>(Wv, wb + 2 * (size_t)NW, NW);
    cvt_kernel<<<NW / 1024, blk, 0, stream>>>(Wo, wb + 3 * (size_t)NW, NW);

    // Fused QKV projection: qkv[ROWS][1536] = x @ [Wq|Wk|Wv]^T + [bq|bk|bv]
    dim3 g1(1536 / 128, ROWS / 128);
    gemm_bt<<<g1, blk, 0, stream>>>(xb, 512,
                                    wb, wb + (size_t)NW, wb + 2 * (size_t)NW,
                                    bq, bk, bv, qkv, nullptr, 1536);

    // Attention: one wave per (b,h); att overwrites xb (x no longer needed)
    dim3 g2((NB * NHEADS) / 4);
    attn_kernel<<<g2, blk, 0, stream>>>(qkv, dist, scale, power, xb);

    // Output projection (fp32 out): out = att @ Wo^T + bo
    dim3 g3(512 / 128, ROWS / 128);
    gemm_bt<<<g3, blk, 0, stream>>>(xb, 512,
                                    wb + 3 * (size_t)NW, wb + 3 * (size_t)NW, wb + 3 * (size_t)NW,
                                    bo, bo, bo, nullptr, out, 512);
}

// Round 2
// 813.380 us; speedup vs baseline: 1.1708x; 1.0269x over previous
//
#include <hip/hip_runtime.h>
#include <stdint.h>

#define D_MODEL 512
#define NHEADS 8
#define DK 64
#define NB 8192
#define NTOK 14
#define ROWS (NB*NTOK)   // 114688

typedef unsigned short ushort_t;
typedef __attribute__((ext_vector_type(8))) short short8;
typedef __attribute__((ext_vector_type(4))) short short4v;
typedef __attribute__((ext_vector_type(4))) float f32x4;

__device__ __forceinline__ float bf2f(ushort_t u) {
    return __uint_as_float(((unsigned int)u) << 16);
}
__device__ __forceinline__ ushort_t f2bf(float f) {
    unsigned int u = __float_as_uint(f);
    unsigned int r = (u + 0x7FFFu + ((u >> 16) & 1u)) >> 16;
    return (ushort_t)r;
}

// async 16B global->LDS: lds dest must be wave-uniform base; HW deposits lane i at base + i*16B
__device__ __forceinline__ void async_copy16(const ushort_t* g, ushort_t* l) {
    __builtin_amdgcn_global_load_lds(
        (const __attribute__((address_space(1))) void*)g,
        (__attribute__((address_space(3))) void*)l,
        16, 0, 0);
}

// counted vmem wait + raw barrier (NOT __syncthreads: that drains vmcnt(0))
#define VM_WAIT(n) asm volatile("s_waitcnt vmcnt(" #n ")" ::: "memory")
#define BARRIER()  do { asm volatile("s_barrier" ::: "memory"); \
                        __builtin_amdgcn_sched_barrier(0); } while (0)

// fp32 -> bf16 conversion (rne), 4 elems/thread
__global__ void cvt_kernel(const float* __restrict__ src, ushort_t* __restrict__ dst, int n)
{
    int i = (blockIdx.x * blockDim.x + threadIdx.x) * 4;
    if (i + 3 < n) {
        float4 v = *(const float4*)(src + i);
        short4v o;
        o[0] = (short)f2bf(v.x);
        o[1] = (short)f2bf(v.y);
        o[2] = (short)f2bf(v.z);
        o[3] = (short)f2bf(v.w);
        *(short4v*)(dst + i) = o;
    }
}

// C[M x *] = A[M x 512] @ W^T + bias. A/W bf16, bias fp32, acc fp32.
// BM=256 BN=128 BK=32, 512 threads = 8 waves (4M x 2N), 64x64 per wave.
// Triple-buffered LDS (3 x 24KB) + counted vmcnt(3) pipeline: K-tile t+2's
// global_load_lds stays in flight across the barrier; only t+1's loads
// (issued a full K-tile of MFMA ago) are waited. vmcnt never drains mid-loop.
// LDS XOR swizzle (slot ^= (row>>1)&3) applied as inverse on the GLOBAL source
// (global_load_lds writes linearly) + on the ds_read address: 16-lane fragment
// reads spread over 8 distinct 16B slots -> 2-way bank aliasing (free).
__global__ __launch_bounds__(512, 2) void gemm_bt(
    const ushort_t* __restrict__ A, int lda,
    const ushort_t* __restrict__ W0, const ushort_t* __restrict__ W1, const ushort_t* __restrict__ W2,
    const float* __restrict__ b0, const float* __restrict__ b1, const float* __restrict__ b2,
    ushort_t* __restrict__ Cb, float* __restrict__ Cf, int ldc)
{
    // 3 buffers: A[256][32] = 8192 ushorts + B[128][32] = 4096 ushorts each
    __shared__ __align__(16) char Shm[73728];
    ushort_t* const shm = (ushort_t*)Shm;

    // bijective XCD chunk remap (both grids are %8 == 0, formula handles any)
    const int nwg = gridDim.x * gridDim.y;
    const int wg  = blockIdx.y * gridDim.x + blockIdx.x;
    const int q8  = nwg >> 3, r8 = nwg & 7;
    const int xcd = wg & 7, idx = wg >> 3;
    const int cbase = (xcd < r8) ? xcd * (q8 + 1) : r8 * (q8 + 1) + (xcd - r8) * q8;
    const int newid = cbase + idx;
    const int ctile = newid % gridDim.x;      // col tile fast-varying within an XCD chunk
    const int rtile = newid / gridDim.x;

    const int m0 = rtile * 256;
    const int n0 = ctile * 128;
    const int wsel = n0 >> 9;
    const ushort_t* W    = (wsel == 0) ? W0 : ((wsel == 1) ? W1 : W2);
    const float*    bias = (wsel == 0) ? b0 : ((wsel == 1) ? b1 : b2);
    const int nw = n0 & 511;

    const int tid  = threadIdx.x;
    const int lane = tid & 63;
    const int wave = tid >> 6;
    const int quad = lane >> 4;
    const int c    = lane & 15;
    const int wm   = (wave >> 1) * 64;   // wave M offset (4 rows of waves)
    const int wn   = (wave & 1) * 64;    // wave N offset (2 cols of waves)

    // ---- staging source constants (per thread) ----
    // A tile: 256 rows x 4 slots of 16B = 1024 chunks -> 2 gloads; B: 512 chunks -> 1
    const int sr0 = tid >> 2;            // rows 0..127   (A rnd0, B)
    const int sr1 = 128 + sr0;           // rows 128..255 (A rnd1)
    const int sl  = tid & 3;
    const int sA0 = sl ^ ((sr0 >> 1) & 3);   // inverse-swizzled source slot
    const int sA1 = sl ^ ((sr1 >> 1) & 3);
    const ushort_t* ga0 = A + (size_t)(m0 + sr0) * lda + sA0 * 8;
    const ushort_t* ga1 = A + (size_t)(m0 + sr1) * lda + sA1 * 8;
    const ushort_t* gb0 = W + (size_t)(nw + sr0) * 512 + sA0 * 8;

    // LDS deposit bases (wave-uniform, ushort units)
    const int ldA0 = wave * 512;
    const int ldA1 = 4096 + wave * 512;
    const int ldB0 = wave * 512;

    // rotating buffer pointers (ushort units): per-buffer stride 12288
    ushort_t* pa0 = shm;           ushort_t* pb0 = shm + 8192;
    ushort_t* pa1 = shm + 12288;   ushort_t* pb1 = shm + 20480;
    ushort_t* pa2 = shm + 24576;   ushort_t* pb2 = shm + 32768;

    // ---- fragment ds_read offsets (swizzled, per thread, ushort units) ----
    int raA[4], raB[4];
    #pragma unroll
    for (int i = 0; i < 4; ++i) {
        int R  = wm + i * 16 + c;
        raA[i] = R * 32 + (quad ^ ((R >> 1) & 3)) * 8;
        int R2 = wn + i * 16 + c;
        raB[i] = R2 * 32 + (quad ^ ((R2 >> 1) & 3)) * 8;
    }

    f32x4 acc[4][4];
    #pragma unroll
    for (int i = 0; i < 4; ++i)
        #pragma unroll
        for (int j = 0; j < 4; ++j)
            acc[i][j] = (f32x4){0.f, 0.f, 0.f, 0.f};

    // ---- prologue: stage K-tiles 0 and 1 (6 loads in flight) ----
    async_copy16(ga0,      pa0 + ldA0);
    async_copy16(ga1,      pa0 + ldA1);
    async_copy16(gb0,      pb0 + ldB0);
    async_copy16(ga0 + 32, pa1 + ldA0);
    async_copy16(ga1 + 32, pa1 + ldA1);
    async_copy16(gb0 + 32, pb1 + ldB0);
    VM_WAIT(3);           // K-tile 0 landed (this wave's)
    BARRIER();            // ... and everyone else's

    // ---- main loop: 16 K-tiles of 32 ----
    for (int t = 0; t < 16; ++t) {
        if (t < 14) {     // stage K-tile t+2 into the buffer freed at t-1
            const int kk = (t + 2) * 32;
            async_copy16(ga0 + kk, pa2 + ldA0);
            async_copy16(ga1 + kk, pa2 + ldA1);
            async_copy16(gb0 + kk, pb2 + ldB0);
        }
        __builtin_amdgcn_sched_barrier(0);   // keep stages issued before reads

        short8 af[4], bfr[4];
        #pragma unroll
        for (int i = 0; i < 4; ++i) {
            af[i]  = *(const short8*)(pa0 + raA[i]);
            bfr[i] = *(const short8*)(pb0 + raB[i]);
        }
        __builtin_amdgcn_s_setprio(1);
        #pragma unroll
        for (int i = 0; i < 4; ++i)
            #pragma unroll
            for (int j = 0; j < 4; ++j)
                acc[i][j] = __builtin_amdgcn_mfma_f32_16x16x32_bf16(af[i], bfr[j], acc[i][j], 0, 0, 0);
        __builtin_amdgcn_s_setprio(0);

        if (t < 14) { VM_WAIT(3); }   // t+1 landed; t+2's 3 loads stay in flight
        else        { VM_WAIT(0); }   // tail drain (loads are old, cheap)
        BARRIER();

        ushort_t* ta = pa0; pa0 = pa1; pa1 = pa2; pa2 = ta;
        ushort_t* tb = pb0; pb0 = pb1; pb1 = pb2; pb2 = tb;
    }

    // ---- epilogue: per-wave LDS staging -> coalesced stores ----
    // acc C layout: col = wn + j*16 + c, row = wm + i*16 + quad*4 + r.
    if (Cf == nullptr) {
        // bf16 out: 64x64 wave tile, row stride 72 (pad kills bank conflicts)
        ushort_t* sl2 = shm + wave * 4608;   // 64*72 ushorts per wave
        #pragma unroll
        for (int i = 0; i < 4; ++i)
            #pragma unroll
            for (int j = 0; j < 4; ++j)
                #pragma unroll
                for (int r = 0; r < 4; ++r) {
                    int rl = i * 16 + quad * 4 + r;
                    int cl = j * 16 + c;
                    sl2[rl * 72 + cl] = f2bf(acc[i][j][r] + bias[nw + wn + cl]);
                }
        #pragma unroll
        for (int t = 0; t < 8; ++t) {
            int rl = t * 8 + (lane >> 3);
            int cl = (lane & 7) * 8;
            short8 v = *(const short8*)&sl2[rl * 72 + cl];
            *(short8*)&Cb[(size_t)(m0 + wm + rl) * ldc + n0 + wn + cl] = v;
        }
    } else {
        // fp32 out: two 32x64 half-tiles per wave
        float* slf = (float*)Shm + wave * 2304;   // 32*72 floats per wave
        #pragma unroll
        for (int half = 0; half < 2; ++half) {
            #pragma unroll
            for (int i2 = 0; i2 < 2; ++i2)
                #pragma unroll
                for (int j = 0; j < 4; ++j)
                    #pragma unroll
                    for (int r = 0; r < 4; ++r) {
                        int i  = half * 2 + i2;
                        int rl = i2 * 16 + quad * 4 + r;
                        int cl = j * 16 + c;
                        slf[rl * 72 + cl] = acc[i][j][r] + bias[nw + wn + cl];
                    }
            #pragma unroll
            for (int t = 0; t < 8; ++t) {
                int rl = t * 4 + (lane >> 4);
                int cl = (lane & 15) * 4;
                f32x4 v = *(const f32x4*)&slf[rl * 72 + cl];
                *(f32x4*)&Cf[(size_t)(m0 + wm + half * 32 + rl) * ldc + n0 + wn + cl] = v;
            }
        }
    }
}

// One wave per (b, h). QKV: [ROWS][1536] bf16 (Q|K|V). O: [ROWS][512] bf16.
__global__ __launch_bounds__(256, 4) void attn_kernel(
    const ushort_t* __restrict__ QKV,
    const float* __restrict__ dist,
    const float* __restrict__ scale_p,
    const float* __restrict__ power_p,
    ushort_t* __restrict__ O)
{
    __shared__ __align__(16) ushort_t Pl[4][16 * 32];
    __shared__ __align__(16) ushort_t Vt[4][64 * 16];   // per-wave V^T: [dk][key]

    const int tid  = threadIdx.x;
    const int lane = tid & 63;
    const int wave = tid >> 6;
    const int id   = blockIdx.x * 4 + wave;   // b*8 + h
    const int b    = id >> 3;
    const int h    = id & 7;
    const int quad = lane >> 4;
    const int c    = lane & 15;

    const float scale = scale_p[0];
    const float power = power_p[0];

    const size_t rowbase = (size_t)b * NTOK;
    const int mrow = (c < NTOK) ? c : (NTOK - 1);

    // ---- stage V^T into LDS: lane covers row m = lane>>2, 16 dk at (lane&3)*16
    {
        int m  = lane >> 2;           // 0..15 (rows 14,15 zero-padded)
        int d0 = (lane & 3) * 16;
        short8 v0 = 0, v1 = 0;
        if (m < NTOK) {
            const ushort_t* vp = QKV + (rowbase + m) * 1536 + 1024 + h * 64 + d0;
            v0 = *(const short8*)vp;
            v1 = *(const short8*)(vp + 8);
        }
        #pragma unroll
        for (int j = 0; j < 8; ++j) {
            Vt[wave][(d0 + j) * 16 + m]     = (ushort_t)v0[j];
            Vt[wave][(d0 + 8 + j) * 16 + m] = (ushort_t)v1[j];
        }
    }

    // Q as A-operand (m = query = c, k = dk), K as B-operand (n = key = c, k = dk)
    const ushort_t* qp = QKV + (rowbase + mrow) * 1536 + h * 64 + quad * 8;
    short8 aq0 = *(const short8*)qp;
    short8 aq1 = *(const short8*)(qp + 32);
    const ushort_t* kp = QKV + (rowbase + mrow) * 1536 + 512 + h * 64 + quad * 8;
    short8 bk0 = *(const short8*)kp;
    short8 bk1 = *(const short8*)(kp + 32);

    f32x4 S = (f32x4){0.f, 0.f, 0.f, 0.f};
    S = __builtin_amdgcn_mfma_f32_16x16x32_bf16(aq0, bk0, S, 0, 0, 0);
    S = __builtin_amdgcn_mfma_f32_16x16x32_bf16(aq1, bk1, S, 0, 0, 0);

    // softmax over cols (key index) per row; C layout: col=c, row=quad*4+r
    float p4[4];
    #pragma unroll
    for (int r = 0; r < 4; ++r) {
        int row = quad * 4 + r;
        float s;
        if (c < NTOK && row < NTOK) {
            float d  = dist[row * NTOK + c];
            float dp = (d > 0.f) ? __expf(power * __logf(d)) : 0.f;
            float pri = scale / (1.f + dp);
            s = S[r] * 0.125f * pri;      // 1/sqrt(64)
        } else if (row >= NTOK) {
            s = 0.f;                       // garbage row, keep finite
        } else {
            s = -INFINITY;                 // col >= NTOK: excluded
        }
        float smax = s;
        #pragma unroll
        for (int off = 1; off < 16; off <<= 1)
            smax = fmaxf(smax, __shfl_xor(smax, off));
        float e = (c < NTOK) ? __expf(s - smax) : 0.f;
        float l = e;
        #pragma unroll
        for (int off = 1; off < 16; off <<= 1)
            l += __shfl_xor(l, off);
        p4[r] = e / l;
    }

    // P (C layout) -> LDS -> A-operand layout. Zero k=16..31 pad region.
    #pragma unroll
    for (int z = 0; z < 4; ++z) {
        int idx = lane * 4 + z;           // 0..255 over 16x16 pad region
        int zr = idx >> 4, zc = idx & 15;
        Pl[wave][zr * 32 + 16 + zc] = 0;
    }
    #pragma unroll
    for (int r = 0; r < 4; ++r)
        Pl[wave][(quad * 4 + r) * 32 + c] = f2bf(p4[r]);

    short8 pf = *(const short8*)&Pl[wave][c * 32 + quad * 8];

    // V as B-operand per 16-col dk tile: n = dk = t*16+c, k = key = quad*8+j
    f32x4 o[4];
    #pragma unroll
    for (int t = 0; t < 4; ++t) {
        short8 vf = *(const short8*)&Vt[wave][(t * 16 + c) * 16 + quad * 8];
        f32x4 z = (f32x4){0.f, 0.f, 0.f, 0.f};
        o[t] = __builtin_amdgcn_mfma_f32_16x16x32_bf16(pf, vf, z, 0, 0, 0);
    }

    #pragma unroll
    for (int r = 0; r < 4; ++r) {
        int row = quad * 4 + r;
        if (row < NTOK) {
            #pragma unroll
            for (int t = 0; t < 4; ++t)
                O[(rowbase + row) * 512 + h * 64 + t * 16 + c] = f2bf(o[t][r]);
        }
    }
}

extern "C" void kernel_launch(void* const* d_in, const int* in_sizes, int n_in,
                              void* d_out, int out_size, void* d_ws, size_t ws_size,
                              hipStream_t stream)
{
    const float* x     = (const float*)d_in[0];
    const float* Wq    = (const float*)d_in[1];
    const float* bq    = (const float*)d_in[2];
    const float* Wk    = (const float*)d_in[3];
    const float* bk    = (const float*)d_in[4];
    const float* Wv    = (const float*)d_in[5];
    const float* bv    = (const float*)d_in[6];
    const float* Wo    = (const float*)d_in[7];
    const float* bo    = (const float*)d_in[8];
    const float* scale = (const float*)d_in[9];
    const float* power = (const float*)d_in[10];
    const float* dist  = (const float*)d_in[11];

    float* out = (float*)d_out;

    // ws layout (bf16): [xb / att : ROWS*512][wb : 4*512*512][qkv : ROWS*1536]
    ushort_t* xb  = (ushort_t*)d_ws;                  // x bf16; reused as att
    ushort_t* wb  = xb + (size_t)ROWS * 512;
    ushort_t* qkv = wb + (size_t)4 * 512 * 512;

    dim3 blk256(256);
    dim3 blk512(512);

    // fp32 -> bf16 converts
    const int NX = ROWS * 512;
    const int NW = 512 * 512;
    cvt_kernel<<<NX / 1024, blk256, 0, stream>>>(x,  xb, NX);
    cvt_kernel<<<NW / 1024, blk256, 0, stream>>>(Wq, wb + 0 * (size_t)NW, NW);
    cvt_kernel<<<NW / 1024, blk256, 0, stream>>>(Wk, wb + 1 * (size_t)NW, NW);
    cvt_kernel<<<NW / 1024, blk256, 0, stream>>>(Wv, wb + 2 * (size_t)NW, NW);
    cvt_kernel<<<NW / 1024, blk256, 0, stream>>>(Wo, wb + 3 * (size_t)NW, NW);

    // Fused QKV projection: qkv[ROWS][1536] = x @ [Wq|Wk|Wv]^T + [bq|bk|bv]
    dim3 g1(1536 / 128, ROWS / 256);
    gemm_bt<<<g1, blk512, 0, stream>>>(xb, 512,
                                       wb, wb + (size_t)NW, wb + 2 * (size_t)NW,
                                       bq, bk, bv, qkv, nullptr, 1536);

    // Attention: one wave per (b,h); att overwrites xb (x no longer needed)
    dim3 g2((NB * NHEADS) / 4);
    attn_kernel<<<g2, blk256, 0, stream>>>(qkv, dist, scale, power, xb);

    // Output projection (fp32 out): out = att @ Wo^T + bo
    dim3 g3(512 / 128, ROWS / 256);
    gemm_bt<<<g3, blk512, 0, stream>>>(xb, 512,
                                       wb + 3 * (size_t)NW, wb + 3 * (size_t)NW, wb + 3 * (size_t)NW,
                                       bo, bo, bo, nullptr, out, 512);
}